// Round 2
// baseline (657.192 us; speedup 1.0000x reference)
//
#include <hip/hip_runtime.h>
#include <hip/hip_fp16.h>

// ---------------------------------------------------------------------------
// GATLayer reduces to:  z = h @ Wfc.T ;  h_out[v] = mean_{e: dst[e]==v} z[src[e]]
// (entmax over singleton dim == 1; entmax over a constant segment == 1/deg)
//
// Fast path (needs ~26.1 MB ws): count -> scan(in place) -> CSR scatter ->
//   gemm(z fp16) -> per-node mean gather.
// Fallback (needs ~13.2 MB ws): count -> gemm(z fp16) -> atomic scatter-add
//   into out -> scale by 1/deg.
// ---------------------------------------------------------------------------

#define WS_ALIGN(x) (((x) + (size_t)255) & ~(size_t)255)

__device__ inline unsigned pack_h2(float a, float b) {
    __half2 h = __floats2half2_rn(a, b);
    return *reinterpret_cast<unsigned*>(&h);
}

__global__ __launch_bounds__(256) void count_deg(const int* __restrict__ dst,
                                                 int* __restrict__ cnt, int E) {
    int e = blockIdx.x * 256 + threadIdx.x;
    if (e < E) atomicAdd(&cnt[dst[e]], 1);
}

// per-block (1024 elems) sums of cnt
__global__ __launch_bounds__(256) void scan_block_sums(const int* __restrict__ cnt,
                                                       int* __restrict__ bsum, int N) {
    __shared__ int sd[256];
    int base = blockIdx.x * 1024;
    int s = 0;
    for (int j = threadIdx.x; j < 1024; j += 256) {
        int i = base + j;
        s += (i < N) ? cnt[i] : 0;
    }
    sd[threadIdx.x] = s;
    __syncthreads();
    for (int off = 128; off > 0; off >>= 1) {
        if (threadIdx.x < off) sd[threadIdx.x] += sd[threadIdx.x + off];
        __syncthreads();
    }
    if (threadIdx.x == 0) bsum[blockIdx.x] = sd[0];
}

// single-block exclusive scan of block sums (nb <= 1024)
__global__ __launch_bounds__(1024) void scan_top(int* __restrict__ bsum, int nb) {
    __shared__ int sd[1024];
    int t = threadIdx.x;
    int v = (t < nb) ? bsum[t] : 0;
    sd[t] = v;
    __syncthreads();
    for (int off = 1; off < 1024; off <<= 1) {
        int x = (t >= off) ? sd[t - off] : 0;
        __syncthreads();
        sd[t] += x;
        __syncthreads();
    }
    if (t < nb) bsum[t] = sd[t] - v;  // exclusive
}

// in-place: cnt[] -> exclusive offsets
__global__ __launch_bounds__(256) void scan_final(int* __restrict__ offs,
                                                  const int* __restrict__ bsum, int N) {
    __shared__ int sd[256];
    int base = blockIdx.x * 1024;
    int idx0 = base + threadIdx.x * 4;
    int v[4];
    int s = 0;
#pragma unroll
    for (int j = 0; j < 4; j++) {
        int i = idx0 + j;
        v[j] = (i < N) ? offs[i] : 0;
        s += v[j];
    }
    sd[threadIdx.x] = s;
    __syncthreads();
    int own = s;
    for (int o = 1; o < 256; o <<= 1) {
        int x = (threadIdx.x >= o) ? sd[threadIdx.x - o] : 0;
        __syncthreads();
        sd[threadIdx.x] += x;
        __syncthreads();
    }
    int run = sd[threadIdx.x] - own + bsum[blockIdx.x];
#pragma unroll
    for (int j = 0; j < 4; j++) {
        int i = idx0 + j;
        if (i < N) offs[i] = run;
        run += v[j];
    }
}

// scatter; leaves offs[] shifted: offs_after[d] == orig_offs[d+1]
__global__ __launch_bounds__(256) void scatter_src(const int* __restrict__ src,
                                                   const int* __restrict__ dst,
                                                   int* __restrict__ offs,
                                                   int* __restrict__ ssrc, int E) {
    int e = blockIdx.x * 256 + threadIdx.x;
    if (e < E) {
        int d = dst[e];
        int pos = atomicAdd(&offs[d], 1);
        ssrc[pos] = src[e];
    }
}

// z[row][c] = sum_k h[row][k] * W[c][k], stored fp16. W (32 KB) in LDS,
// wave-uniform broadcast reads. One thread per row, 64 fp32 accumulators.
__global__ __launch_bounds__(256) void gemm_z(const float* __restrict__ h,
                                              const float* __restrict__ W,
                                              __half* __restrict__ z, int N) {
    __shared__ float Wl[64 * 128];
    for (int j = threadIdx.x; j < 2048; j += 256) {
        reinterpret_cast<float4*>(Wl)[j] = reinterpret_cast<const float4*>(W)[j];
    }
    __syncthreads();
    int row = blockIdx.x * 256 + threadIdx.x;
    if (row >= N) return;
    float acc[64];
#pragma unroll
    for (int c = 0; c < 64; c++) acc[c] = 0.f;
    const float4* hr = reinterpret_cast<const float4*>(&h[(size_t)row * 128]);
    for (int kv = 0; kv < 32; kv++) {
        float4 hv = hr[kv];
#pragma unroll
        for (int c = 0; c < 64; c++) {
            float4 wv = *reinterpret_cast<const float4*>(&Wl[c * 128 + kv * 4]);
            acc[c] += hv.x * wv.x + hv.y * wv.y + hv.z * wv.z + hv.w * wv.w;
        }
    }
    uint4* zr = reinterpret_cast<uint4*>(&z[(size_t)row * 64]);
#pragma unroll
    for (int c = 0; c < 8; c++) {
        uint4 pk;
        pk.x = pack_h2(acc[8 * c + 0], acc[8 * c + 1]);
        pk.y = pack_h2(acc[8 * c + 2], acc[8 * c + 3]);
        pk.z = pack_h2(acc[8 * c + 4], acc[8 * c + 5]);
        pk.w = pack_h2(acc[8 * c + 6], acc[8 * c + 7]);
        zr[c] = pk;
    }
}

// one wave per node; lane = output column (out_dim == 64 == wave size)
// offs[] is post-scatter (shifted): s1 = offs[v], s0 = v ? offs[v-1] : 0
__global__ __launch_bounds__(256) void gather_avg(const __half* __restrict__ z,
                                                  const int* __restrict__ ssrc,
                                                  const int* __restrict__ offs,
                                                  float* __restrict__ out, int N) {
    int node = blockIdx.x * 4 + (threadIdx.x >> 6);
    int lane = threadIdx.x & 63;
    if (node >= N) return;
    int s1 = offs[node];
    int s0 = (node > 0) ? offs[node - 1] : 0;
    float acc = 0.f;
    for (int e = s0; e < s1; e += 64) {
        int nrem = s1 - e;
        int vsrc = (lane < nrem) ? ssrc[e + lane] : 0;
        int cnt = nrem < 64 ? nrem : 64;
        for (int i = 0; i < cnt; i++) {
            int s = __shfl(vsrc, i);
            acc += __half2float(z[(size_t)s * 64 + lane]);
        }
    }
    int d = s1 - s0;
    if (d > 0) acc *= (1.0f / (float)d);
    out[(size_t)node * 64 + lane] = acc;
}

// ---- fallback path (small ws): atomic scatter-add, then scale by 1/deg ----
__global__ __launch_bounds__(256) void edge_add(const __half* __restrict__ z,
                                                const int* __restrict__ src,
                                                const int* __restrict__ dst,
                                                float* __restrict__ out, int E) {
    int e = blockIdx.x * 4 + (threadIdx.x >> 6);
    int lane = threadIdx.x & 63;
    if (e >= E) return;
    int s = src[e];
    int d = dst[e];
    float v = __half2float(z[(size_t)s * 64 + lane]);
    atomicAdd(&out[(size_t)d * 64 + lane], v);
}

__global__ __launch_bounds__(256) void scale_out(float* __restrict__ out,
                                                 const int* __restrict__ deg, int N) {
    int v = blockIdx.x * 4 + (threadIdx.x >> 6);
    int lane = threadIdx.x & 63;
    if (v >= N) return;
    int d = deg[v];
    if (d > 0) out[(size_t)v * 64 + lane] *= (1.0f / (float)d);
}

extern "C" void kernel_launch(void* const* d_in, const int* in_sizes, int n_in,
                              void* d_out, int out_size, void* d_ws, size_t ws_size,
                              hipStream_t stream) {
    const float* h   = (const float*)d_in[0];
    const int*   src = (const int*)d_in[2];
    const int*   dst = (const int*)d_in[3];
    const float* Wfc = (const float*)d_in[4];
    float*       out = (float*)d_out;

    int N = in_sizes[0] / 128;
    int E = in_sizes[2];
    (void)n_in; (void)out_size;

    size_t sz_z    = WS_ALIGN((size_t)N * 64 * sizeof(__half));
    size_t sz_offs = WS_ALIGN((size_t)(N + 1) * sizeof(int));
    size_t sz_bsum = WS_ALIGN((size_t)1024 * sizeof(int));
    size_t sz_ssrc = WS_ALIGN((size_t)E * sizeof(int));

    size_t need_csr = sz_z + sz_offs + sz_bsum + sz_ssrc;

    char* ws = (char*)d_ws;
    __half* z    = (__half*)ws;
    int*    offs = (int*)(ws + sz_z);
    int*    bsum = (int*)(ws + sz_z + sz_offs);
    int*    ssrc = (int*)(ws + sz_z + sz_offs + sz_bsum);

    int NB = (N + 1023) / 1024;

    if (ws_size >= need_csr) {
        // ---- fast CSR path ----
        hipMemsetAsync(offs, 0, (size_t)(N + 1) * sizeof(int), stream);
        count_deg<<<(E + 255) / 256, 256, 0, stream>>>(dst, offs, E);
        scan_block_sums<<<NB, 256, 0, stream>>>(offs, bsum, N);
        scan_top<<<1, 1024, 0, stream>>>(bsum, NB);
        scan_final<<<NB, 256, 0, stream>>>(offs, bsum, N);
        scatter_src<<<(E + 255) / 256, 256, 0, stream>>>(src, dst, offs, ssrc, E);
        gemm_z<<<(N + 255) / 256, 256, 0, stream>>>(h, Wfc, z, N);
        gather_avg<<<(N + 3) / 4, 256, 0, stream>>>(z, ssrc, offs, out, N);
    } else {
        // ---- fallback: atomic scatter-add ----
        int* deg = offs;  // reuse slot after z
        hipMemsetAsync(deg, 0, (size_t)N * sizeof(int), stream);
        hipMemsetAsync(out, 0, (size_t)N * 64 * sizeof(float), stream);
        count_deg<<<(E + 255) / 256, 256, 0, stream>>>(dst, deg, E);
        gemm_z<<<(N + 255) / 256, 256, 0, stream>>>(h, Wfc, z, N);
        edge_add<<<(E + 3) / 4, 256, 0, stream>>>(z, src, dst, out, E);
        scale_out<<<(N + 3) / 4, 256, 0, stream>>>(out, deg, N);
    }
}

// Round 5
// 436.689 us; speedup vs baseline: 1.5049x; 1.5049x over previous
//
#include <hip/hip_runtime.h>
#include <hip/hip_fp16.h>

// ---------------------------------------------------------------------------
// GATLayer reduces to:  z = h @ Wfc.T ;  h_out[v] = mean_{e: dst[e]==v} z[src[e]]
// (entmax over singleton dim == 1; entmax over a constant segment == 1/deg)
//
// Fast path: count -> scan -> bucket-bin (49 x 2048-node buckets, packed u32,
//   binned lives in d_out scratch -- NO aliasing with z) -> L2-local CSR place
//   -> gemm (z fp16) -> mean gather (fully overwrites d_out).
// ---------------------------------------------------------------------------

#define WS_ALIGN(x) (((x) + (size_t)255) & ~(size_t)255)
#define BBITS 11   // 2048 nodes per bucket

__device__ inline unsigned pack_h2(float a, float b) {
    __half2 h = __floats2half2_rn(a, b);
    return *reinterpret_cast<unsigned*>(&h);
}

__global__ __launch_bounds__(256) void count_deg(const int* __restrict__ dst,
                                                 int* __restrict__ cnt, int E) {
    int e = blockIdx.x * 256 + threadIdx.x;
    if (e < E) atomicAdd(&cnt[dst[e]], 1);
}

// per-block (1024 elems) sums of cnt
__global__ __launch_bounds__(256) void scan_block_sums(const int* __restrict__ cnt,
                                                       int* __restrict__ bsum, int N) {
    __shared__ int sd[256];
    int base = blockIdx.x * 1024;
    int s = 0;
    for (int j = threadIdx.x; j < 1024; j += 256) {
        int i = base + j;
        s += (i < N) ? cnt[i] : 0;
    }
    sd[threadIdx.x] = s;
    __syncthreads();
    for (int off = 128; off > 0; off >>= 1) {
        if (threadIdx.x < off) sd[threadIdx.x] += sd[threadIdx.x + off];
        __syncthreads();
    }
    if (threadIdx.x == 0) bsum[blockIdx.x] = sd[0];
}

// single-block exclusive scan of block sums (nb <= 1024)
__global__ __launch_bounds__(1024) void scan_top(int* __restrict__ bsum, int nb) {
    __shared__ int sd[1024];
    int t = threadIdx.x;
    int v = (t < nb) ? bsum[t] : 0;
    sd[t] = v;
    __syncthreads();
    for (int off = 1; off < 1024; off <<= 1) {
        int x = (t >= off) ? sd[t - off] : 0;
        __syncthreads();
        sd[t] += x;
        __syncthreads();
    }
    if (t < nb) bsum[t] = sd[t] - v;  // exclusive
}

// in-place: cnt[] -> exclusive offsets
__global__ __launch_bounds__(256) void scan_final(int* __restrict__ offs,
                                                  const int* __restrict__ bsum, int N) {
    __shared__ int sd[256];
    int base = blockIdx.x * 1024;
    int idx0 = base + threadIdx.x * 4;
    int v[4];
    int s = 0;
#pragma unroll
    for (int j = 0; j < 4; j++) {
        int i = idx0 + j;
        v[j] = (i < N) ? offs[i] : 0;
        s += v[j];
    }
    sd[threadIdx.x] = s;
    __syncthreads();
    int own = s;
    for (int o = 1; o < 256; o <<= 1) {
        int x = (threadIdx.x >= o) ? sd[threadIdx.x - o] : 0;
        __syncthreads();
        sd[threadIdx.x] += x;
        __syncthreads();
    }
    int run = sd[threadIdx.x] - own + bsum[blockIdx.x];
#pragma unroll
    for (int j = 0; j < 4; j++) {
        int i = idx0 + j;
        if (i < N) offs[i] = run;
        run += v[j];
    }
}

// cur/bases from exclusive offs (one block, nbuck <= 64)
__global__ __launch_bounds__(64) void init_buckets(const int* __restrict__ offs,
                                                   int* __restrict__ cur,
                                                   int* __restrict__ bases,
                                                   int E, int nbuck) {
    int t = threadIdx.x;
    if (t < nbuck) {
        int v = offs[(size_t)t << BBITS];
        cur[t] = v;
        bases[t] = v;
    }
    if (t == 0) bases[nbuck] = E;
}

// pass A: block-level counting sort into buckets; packed (ld<<17 | src)
__global__ __launch_bounds__(256) void bin_scatter(const int* __restrict__ src,
                                                   const int* __restrict__ dst,
                                                   int* __restrict__ cur,
                                                   unsigned* __restrict__ binned,
                                                   int E) {
    __shared__ int hist[64], gbase[64], cnt2[64];
    int base = blockIdx.x * 8192;
    if (threadIdx.x < 64) { hist[threadIdx.x] = 0; cnt2[threadIdx.x] = 0; }
    __syncthreads();
#pragma unroll 4
    for (int k = 0; k < 32; k++) {
        int e = base + threadIdx.x + k * 256;
        if (e < E) atomicAdd(&hist[dst[e] >> BBITS], 1);
    }
    __syncthreads();
    if (threadIdx.x < 64 && hist[threadIdx.x] > 0)
        gbase[threadIdx.x] = atomicAdd(&cur[threadIdx.x], hist[threadIdx.x]);
    __syncthreads();
#pragma unroll 4
    for (int k = 0; k < 32; k++) {
        int e = base + threadIdx.x + k * 256;
        if (e < E) {
            int d = dst[e];
            int b = d >> BBITS;
            int lo = atomicAdd(&cnt2[b], 1);
            binned[gbase[b] + lo] = ((unsigned)(d & ((1 << BBITS) - 1)) << 17) |
                                    (unsigned)src[e];
        }
    }
}

// pass B: place binned edges into CSR; block's writes stay in one bucket's
// ~200KB ssrc range (L2-local). XCD-swizzled so a bucket's chunks share an XCD.
__global__ __launch_bounds__(256) void csr_place(const unsigned* __restrict__ binned,
                                                 const int* __restrict__ bases,
                                                 int* __restrict__ offs,
                                                 int* __restrict__ ssrc,
                                                 int E, int nbuck, int nwg) {
    __shared__ int sb[65];
    // bijective XCD swizzle: consecutive chunks of a bucket -> same XCD
    int orig = blockIdx.x;
    int q = nwg >> 3, r = nwg & 7;
    int x = orig & 7, idx = orig >> 3;
    int wg = (x < r ? x * (q + 1) : r * (q + 1) + (x - r) * q) + idx;
    for (int j = threadIdx.x; j <= nbuck; j += 256) sb[j] = bases[j];
    __syncthreads();
    int base = wg * 8192;
    int i0 = base + threadIdx.x;
    int b;
    {   // binary search starting bucket for this thread's first index
        int lo = 0, hi = nbuck;
        while (lo < hi) {
            int mid = (lo + hi) >> 1;
            if (sb[mid + 1] <= i0) lo = mid + 1; else hi = mid;
        }
        b = lo;
    }
    for (int k = 0; k < 32; k++) {
        int i = base + threadIdx.x + k * 256;
        if (i < E) {
            while (i >= sb[b + 1]) b++;
            unsigned p = binned[i];
            int d = (b << BBITS) | (int)(p >> 17);
            int s = (int)(p & 0x1FFFFu);
            int pos = atomicAdd(&offs[d], 1);
            ssrc[pos] = s;
        }
    }
}

// generic fallback scatter (non-localized)
__global__ __launch_bounds__(256) void scatter_src(const int* __restrict__ src,
                                                   const int* __restrict__ dst,
                                                   int* __restrict__ offs,
                                                   int* __restrict__ ssrc, int E) {
    int e = blockIdx.x * 256 + threadIdx.x;
    if (e < E) {
        int d = dst[e];
        int pos = atomicAdd(&offs[d], 1);
        ssrc[pos] = src[e];
    }
}

// z[row][c] = sum_k h[row][k] * W[c][k], stored fp16. W (32 KB) in LDS,
// wave-uniform broadcast reads. One thread per row, 64 fp32 accumulators.
__global__ __launch_bounds__(256) void gemm_z(const float* __restrict__ h,
                                              const float* __restrict__ W,
                                              __half* __restrict__ z, int N) {
    __shared__ float Wl[64 * 128];
    for (int j = threadIdx.x; j < 2048; j += 256) {
        reinterpret_cast<float4*>(Wl)[j] = reinterpret_cast<const float4*>(W)[j];
    }
    __syncthreads();
    int row = blockIdx.x * 256 + threadIdx.x;
    if (row >= N) return;
    float acc[64];
#pragma unroll
    for (int c = 0; c < 64; c++) acc[c] = 0.f;
    const float4* hr = reinterpret_cast<const float4*>(&h[(size_t)row * 128]);
    for (int kv = 0; kv < 32; kv++) {
        float4 hv = hr[kv];
#pragma unroll
        for (int c = 0; c < 64; c++) {
            float4 wv = *reinterpret_cast<const float4*>(&Wl[c * 128 + kv * 4]);
            acc[c] += hv.x * wv.x + hv.y * wv.y + hv.z * wv.z + hv.w * wv.w;
        }
    }
    uint4* zr = reinterpret_cast<uint4*>(&z[(size_t)row * 64]);
#pragma unroll
    for (int c = 0; c < 8; c++) {
        uint4 pk;
        pk.x = pack_h2(acc[8 * c + 0], acc[8 * c + 1]);
        pk.y = pack_h2(acc[8 * c + 2], acc[8 * c + 3]);
        pk.z = pack_h2(acc[8 * c + 4], acc[8 * c + 5]);
        pk.w = pack_h2(acc[8 * c + 6], acc[8 * c + 7]);
        zr[c] = pk;
    }
}

// one wave per node; lane = output column. offs[] is post-scatter (shifted):
// s1 = offs[v], s0 = v ? offs[v-1] : 0. Inner loop unrolled x4 for MLP.
__global__ __launch_bounds__(256) void gather_avg(const __half* __restrict__ z,
                                                  const int* __restrict__ ssrc,
                                                  const int* __restrict__ offs,
                                                  float* __restrict__ out, int N) {
    int node = blockIdx.x * 4 + (threadIdx.x >> 6);
    int lane = threadIdx.x & 63;
    if (node >= N) return;
    int s1 = offs[node];
    int s0 = (node > 0) ? offs[node - 1] : 0;
    float a0 = 0.f, a1 = 0.f, a2 = 0.f, a3 = 0.f;
    for (int e = s0; e < s1; e += 64) {
        int nrem = s1 - e;
        int cnt = nrem < 64 ? nrem : 64;
        int vsrc = (lane < nrem) ? ssrc[e + lane] : 0;
        int i = 0;
        for (; i + 4 <= cnt; i += 4) {
            int q0 = __shfl(vsrc, i);
            int q1 = __shfl(vsrc, i + 1);
            int q2 = __shfl(vsrc, i + 2);
            int q3 = __shfl(vsrc, i + 3);
            a0 += __half2float(z[(size_t)q0 * 64 + lane]);
            a1 += __half2float(z[(size_t)q1 * 64 + lane]);
            a2 += __half2float(z[(size_t)q2 * 64 + lane]);
            a3 += __half2float(z[(size_t)q3 * 64 + lane]);
        }
        for (; i < cnt; i++) {
            int q = __shfl(vsrc, i);
            a0 += __half2float(z[(size_t)q * 64 + lane]);
        }
    }
    float acc = (a0 + a1) + (a2 + a3);
    int d = s1 - s0;
    if (d > 0) acc *= (1.0f / (float)d);
    out[(size_t)node * 64 + lane] = acc;
}

// ---- fallback path (small ws): atomic scatter-add, then scale by 1/deg ----
__global__ __launch_bounds__(256) void edge_add(const __half* __restrict__ z,
                                                const int* __restrict__ src,
                                                const int* __restrict__ dst,
                                                float* __restrict__ out, int E) {
    int e = blockIdx.x * 4 + (threadIdx.x >> 6);
    int lane = threadIdx.x & 63;
    if (e >= E) return;
    int s = src[e];
    int d = dst[e];
    float v = __half2float(z[(size_t)s * 64 + lane]);
    atomicAdd(&out[(size_t)d * 64 + lane], v);
}

__global__ __launch_bounds__(256) void scale_out(float* __restrict__ out,
                                                 const int* __restrict__ deg, int N) {
    int v = blockIdx.x * 4 + (threadIdx.x >> 6);
    int lane = threadIdx.x & 63;
    if (v >= N) return;
    int d = deg[v];
    if (d > 0) out[(size_t)v * 64 + lane] *= (1.0f / (float)d);
}

extern "C" void kernel_launch(void* const* d_in, const int* in_sizes, int n_in,
                              void* d_out, int out_size, void* d_ws, size_t ws_size,
                              hipStream_t stream) {
    const float* h   = (const float*)d_in[0];
    const int*   src = (const int*)d_in[2];
    const int*   dst = (const int*)d_in[3];
    const float* Wfc = (const float*)d_in[4];
    float*       out = (float*)d_out;

    int N = in_sizes[0] / 128;
    int E = in_sizes[2];
    (void)n_in;

    int nbuck = (N + (1 << BBITS) - 1) >> BBITS;

    size_t sz_z    = WS_ALIGN((size_t)N * 64 * sizeof(__half));
    size_t sz_offs = WS_ALIGN((size_t)(N + 1) * sizeof(int));
    size_t sz_bsum = WS_ALIGN((size_t)1024 * sizeof(int));
    size_t sz_bkt  = WS_ALIGN((size_t)130 * sizeof(int));
    size_t sz_ssrc = WS_ALIGN((size_t)E * sizeof(int));

    size_t need_fast = sz_z + sz_offs + sz_bsum + sz_bkt + sz_ssrc;

    char* ws = (char*)d_ws;
    __half* z    = (__half*)ws;
    int*    offs = (int*)(ws + sz_z);
    int*    bsum = (int*)(ws + sz_z + sz_offs);
    int*    cur  = (int*)(ws + sz_z + sz_offs + sz_bsum);
    int*    bases = cur + 65;
    int*    ssrc = (int*)(ws + sz_z + sz_offs + sz_bsum + sz_bkt);

    // binned lives in d_out scratch (consumed by csr_place before gather
    // overwrites out) -- deliberately NOT aliased with z.
    unsigned* binned = (unsigned*)d_out;

    int NB = (N + 1023) / 1024;
    int nwgE = (E + 8191) / 8192;

    bool can_bin = (N <= (1 << 17)) && (nbuck <= 64) && (ws_size >= need_fast) &&
                   ((size_t)out_size * sizeof(float) >= (size_t)E * sizeof(unsigned));

    if (can_bin) {
        hipMemsetAsync(offs, 0, (size_t)(N + 1) * sizeof(int), stream);
        count_deg<<<(E + 255) / 256, 256, 0, stream>>>(dst, offs, E);
        scan_block_sums<<<NB, 256, 0, stream>>>(offs, bsum, N);
        scan_top<<<1, 1024, 0, stream>>>(bsum, NB);
        scan_final<<<NB, 256, 0, stream>>>(offs, bsum, N);
        init_buckets<<<1, 64, 0, stream>>>(offs, cur, bases, E, nbuck);
        bin_scatter<<<nwgE, 256, 0, stream>>>(src, dst, cur, binned, E);
        csr_place<<<nwgE, 256, 0, stream>>>(binned, bases, offs, ssrc, E, nbuck, nwgE);
        gemm_z<<<(N + 255) / 256, 256, 0, stream>>>(h, Wfc, z, N);
        gather_avg<<<(N + 3) / 4, 256, 0, stream>>>(z, ssrc, offs, out, N);
    } else if (ws_size >= need_fast) {
        // generic CSR path (no binning)
        hipMemsetAsync(offs, 0, (size_t)(N + 1) * sizeof(int), stream);
        count_deg<<<(E + 255) / 256, 256, 0, stream>>>(dst, offs, E);
        scan_block_sums<<<NB, 256, 0, stream>>>(offs, bsum, N);
        scan_top<<<1, 1024, 0, stream>>>(bsum, NB);
        scan_final<<<NB, 256, 0, stream>>>(offs, bsum, N);
        scatter_src<<<(E + 255) / 256, 256, 0, stream>>>(src, dst, offs, ssrc, E);
        gemm_z<<<(N + 255) / 256, 256, 0, stream>>>(h, Wfc, z, N);
        gather_avg<<<(N + 3) / 4, 256, 0, stream>>>(z, ssrc, offs, out, N);
    } else {
        // atomic scatter-add fallback
        int* deg = offs;
        hipMemsetAsync(deg, 0, (size_t)N * sizeof(int), stream);
        hipMemsetAsync(out, 0, (size_t)N * 64 * sizeof(float), stream);
        count_deg<<<(E + 255) / 256, 256, 0, stream>>>(dst, deg, E);
        gemm_z<<<(N + 255) / 256, 256, 0, stream>>>(h, Wfc, z, N);
        edge_add<<<(E + 3) / 4, 256, 0, stream>>>(z, src, dst, out, E);
        scale_out<<<(N + 3) / 4, 256, 0, stream>>>(out, deg, N);
    }
}

// Round 6
// 329.957 us; speedup vs baseline: 1.9918x; 1.3235x over previous
//
#include <hip/hip_runtime.h>
#include <hip/hip_fp16.h>

// ---------------------------------------------------------------------------
// GATLayer reduces to:  z = h @ Wfc.T ;  h_out[v] = mean_{e: dst[e]==v} z[src[e]]
// (entmax over singleton dim == 1; entmax over a constant segment == 1/deg)
//
// Fast path: bucket_count (LDS hist, 391 buckets of 256 nodes) -> tiny scan ->
//   bin_scatter (packed (ld<<17|src)) -> gemm (z fp16) -> bucket_gather
//   (per-bucket LDS counting sort + per-node REGISTER gather -> out).
// No global CSR, no per-node global atomics.
// ---------------------------------------------------------------------------

#define WS_ALIGN(x) (((x) + (size_t)255) & ~(size_t)255)
#define BBITS 8
#define BNODES 256            // nodes per bucket
#define CAP 8192              // edges sorted per LDS chunk
#define MAXBUCK 512

__device__ inline unsigned pack_h2(float a, float b) {
    __half2 h = __floats2half2_rn(a, b);
    return *reinterpret_cast<unsigned*>(&h);
}

// ---- per-bucket edge counts via LDS histogram (few atomics per block) ----
__global__ __launch_bounds__(256) void bucket_count(const int* __restrict__ dst,
                                                    int* __restrict__ bcnt,
                                                    int E, int nbuck) {
    __shared__ int h[MAXBUCK];
    for (int i = threadIdx.x; i < nbuck; i += 256) h[i] = 0;
    __syncthreads();
    int base = blockIdx.x * 16384;
    for (int k = 0; k < 64; k++) {
        int e = base + threadIdx.x + k * 256;
        if (e < E) atomicAdd(&h[dst[e] >> BBITS], 1);
    }
    __syncthreads();
    for (int i = threadIdx.x; i < nbuck; i += 256)
        if (h[i]) atomicAdd(&bcnt[i], h[i]);
}

// ---- exclusive scan of bucket counts (1 block, nbuck <= 512) ----
__global__ __launch_bounds__(512) void scan_buckets(const int* __restrict__ bcnt,
                                                    int* __restrict__ bases,
                                                    int* __restrict__ cur,
                                                    int E, int nbuck) {
    __shared__ int sd[512];
    int t = threadIdx.x;
    int v = (t < nbuck) ? bcnt[t] : 0;
    sd[t] = v;
    __syncthreads();
    for (int off = 1; off < 512; off <<= 1) {
        int x = (t >= off) ? sd[t - off] : 0;
        __syncthreads();
        sd[t] += x;
        __syncthreads();
    }
    if (t < nbuck) {
        int ex = sd[t] - v;
        bases[t] = ex;
        cur[t] = ex;
    }
    if (t == 0) bases[nbuck] = E;
}

// ---- bin edges into bucket-contiguous runs, packed (localdst<<17 | src) ----
__global__ __launch_bounds__(256) void bin_scatter(const int* __restrict__ src,
                                                   const int* __restrict__ dst,
                                                   int* __restrict__ cur,
                                                   unsigned* __restrict__ binned,
                                                   int E, int nbuck) {
    __shared__ int hist[MAXBUCK], gbase[MAXBUCK], cnt2[MAXBUCK];
    int base = blockIdx.x * 16384;
    for (int i = threadIdx.x; i < nbuck; i += 256) { hist[i] = 0; cnt2[i] = 0; }
    __syncthreads();
    for (int k = 0; k < 64; k++) {
        int e = base + threadIdx.x + k * 256;
        if (e < E) atomicAdd(&hist[dst[e] >> BBITS], 1);
    }
    __syncthreads();
    for (int i = threadIdx.x; i < nbuck; i += 256)
        if (hist[i]) gbase[i] = atomicAdd(&cur[i], hist[i]);
    __syncthreads();
    for (int k = 0; k < 64; k++) {
        int e = base + threadIdx.x + k * 256;
        if (e < E) {
            int d = dst[e];
            int b = d >> BBITS;
            int lo = atomicAdd(&cnt2[b], 1);
            binned[gbase[b] + lo] = ((unsigned)(d & (BNODES - 1)) << 17) |
                                    (unsigned)src[e];
        }
    }
}

// ---- z = h @ W.T, fp16 out. W (32 KB) in LDS, broadcast reads. ----
__global__ __launch_bounds__(256) void gemm_z(const float* __restrict__ h,
                                              const float* __restrict__ W,
                                              __half* __restrict__ z, int N) {
    __shared__ float Wl[64 * 128];
    for (int j = threadIdx.x; j < 2048; j += 256) {
        reinterpret_cast<float4*>(Wl)[j] = reinterpret_cast<const float4*>(W)[j];
    }
    __syncthreads();
    int row = blockIdx.x * 256 + threadIdx.x;
    if (row >= N) return;
    float acc[64];
#pragma unroll
    for (int c = 0; c < 64; c++) acc[c] = 0.f;
    const float4* hr = reinterpret_cast<const float4*>(&h[(size_t)row * 128]);
    for (int kv = 0; kv < 32; kv++) {
        float4 hv = hr[kv];
#pragma unroll
        for (int c = 0; c < 64; c++) {
            float4 wv = *reinterpret_cast<const float4*>(&Wl[c * 128 + kv * 4]);
            acc[c] += hv.x * wv.x + hv.y * wv.y + hv.z * wv.z + hv.w * wv.w;
        }
    }
    uint4* zr = reinterpret_cast<uint4*>(&z[(size_t)row * 64]);
#pragma unroll
    for (int c = 0; c < 8; c++) {
        uint4 pk;
        pk.x = pack_h2(acc[8 * c + 0], acc[8 * c + 1]);
        pk.y = pack_h2(acc[8 * c + 2], acc[8 * c + 3]);
        pk.z = pack_h2(acc[8 * c + 4], acc[8 * c + 5]);
        pk.w = pack_h2(acc[8 * c + 6], acc[8 * c + 7]);
        zr[c] = pk;
    }
}

// ---- one block per bucket: LDS counting sort + per-node register gather ----
// 1024 threads = 16 waves; wave w owns nodes [w*16, w*16+16) of the bucket.
__global__ __launch_bounds__(1024) void bucket_gather(
        const unsigned* __restrict__ binned,
        const int* __restrict__ bases,
        const __half* __restrict__ z,
        float* __restrict__ out, int N) {
    __shared__ unsigned sed[CAP];       // srcs sorted by local dst (32 KB)
    __shared__ int hist[BNODES];
    __shared__ int ioff[BNODES];        // inclusive offsets (chunk)
    __shared__ int eoff[BNODES];        // exclusive offsets (chunk)
    __shared__ int curs[BNODES];
    __shared__ int degl[BNODES];        // total degree across chunks

    int b = blockIdx.x;
    int s0 = bases[b], s1 = bases[b + 1];
    int tid = threadIdx.x;
    int wid = tid >> 6, lane = tid & 63;

    for (int i = tid; i < BNODES; i += 1024) degl[i] = 0;
    __syncthreads();

    float acc[16];
#pragma unroll
    for (int s = 0; s < 16; s++) acc[s] = 0.f;

    for (int c0 = s0; c0 < s1; c0 += CAP) {
        int cnt = s1 - c0;
        if (cnt > CAP) cnt = CAP;
        // 1) zero hist
        for (int i = tid; i < BNODES; i += 1024) hist[i] = 0;
        __syncthreads();
        // 2) histogram local dst
        for (int i = tid; i < cnt; i += 1024) {
            unsigned p = binned[c0 + i];
            atomicAdd(&hist[(p >> 17) & (BNODES - 1)], 1);
        }
        __syncthreads();
        // 3) scan (256 participants)
        if (tid < BNODES) ioff[tid] = hist[tid];
        __syncthreads();
        for (int off = 1; off < BNODES; off <<= 1) {
            int x = 0;
            if (tid < BNODES && tid >= off) x = ioff[tid - off];
            __syncthreads();
            if (tid < BNODES) ioff[tid] += x;
            __syncthreads();
        }
        if (tid < BNODES) {
            int ex = ioff[tid] - hist[tid];
            eoff[tid] = ex;
            curs[tid] = ex;
            degl[tid] += hist[tid];
        }
        __syncthreads();
        // 4) place (LDS atomics only)
        for (int i = tid; i < cnt; i += 1024) {
            unsigned p = binned[c0 + i];
            int ld = (p >> 17) & (BNODES - 1);
            int pos = atomicAdd(&curs[ld], 1);
            sed[pos] = p & 0x1FFFFu;
        }
        __syncthreads();
        // 5) per-node register gather; lane = output column
#pragma unroll
        for (int s = 0; s < 16; s++) {
            int r = wid * 16 + s;
            int e0 = eoff[r], e1 = ioff[r];
            float f0 = 0.f, f1 = 0.f, f2 = 0.f, f3 = 0.f;
            int e = e0;
            for (; e + 4 <= e1; e += 4) {
                int q0 = sed[e], q1 = sed[e + 1], q2 = sed[e + 2], q3 = sed[e + 3];
                f0 += __half2float(z[(size_t)q0 * 64 + lane]);
                f1 += __half2float(z[(size_t)q1 * 64 + lane]);
                f2 += __half2float(z[(size_t)q2 * 64 + lane]);
                f3 += __half2float(z[(size_t)q3 * 64 + lane]);
            }
            for (; e < e1; e++)
                f0 += __half2float(z[(size_t)sed[e] * 64 + lane]);
            acc[s] += (f0 + f1) + (f2 + f3);
        }
        __syncthreads();   // protect sed/ioff/eoff before next chunk
    }
    // 6) write out (coalesced 256B per node row)
    int node0 = b << BBITS;
#pragma unroll
    for (int s = 0; s < 16; s++) {
        int node = node0 + wid * 16 + s;
        if (node < N) {
            int d = degl[wid * 16 + s];
            float sc = (d > 0) ? 1.0f / (float)d : 0.f;
            out[(size_t)node * 64 + lane] = acc[s] * sc;
        }
    }
}

// ---- fallback path (small ws / odd shapes): atomic scatter-add ----
__global__ __launch_bounds__(256) void count_deg(const int* __restrict__ dst,
                                                 int* __restrict__ cnt, int E) {
    int e = blockIdx.x * 256 + threadIdx.x;
    if (e < E) atomicAdd(&cnt[dst[e]], 1);
}

__global__ __launch_bounds__(256) void edge_add(const __half* __restrict__ z,
                                                const int* __restrict__ src,
                                                const int* __restrict__ dst,
                                                float* __restrict__ out, int E) {
    int e = blockIdx.x * 4 + (threadIdx.x >> 6);
    int lane = threadIdx.x & 63;
    if (e >= E) return;
    int s = src[e];
    int d = dst[e];
    float v = __half2float(z[(size_t)s * 64 + lane]);
    atomicAdd(&out[(size_t)d * 64 + lane], v);
}

__global__ __launch_bounds__(256) void scale_out(float* __restrict__ out,
                                                 const int* __restrict__ deg, int N) {
    int v = blockIdx.x * 4 + (threadIdx.x >> 6);
    int lane = threadIdx.x & 63;
    if (v >= N) return;
    int d = deg[v];
    if (d > 0) out[(size_t)v * 64 + lane] *= (1.0f / (float)d);
}

extern "C" void kernel_launch(void* const* d_in, const int* in_sizes, int n_in,
                              void* d_out, int out_size, void* d_ws, size_t ws_size,
                              hipStream_t stream) {
    const float* h   = (const float*)d_in[0];
    const int*   src = (const int*)d_in[2];
    const int*   dst = (const int*)d_in[3];
    const float* Wfc = (const float*)d_in[4];
    float*       out = (float*)d_out;

    int N = in_sizes[0] / 128;
    int E = in_sizes[2];
    (void)n_in; (void)out_size;

    int nbuck = (N + BNODES - 1) >> BBITS;

    size_t sz_z    = WS_ALIGN((size_t)N * 64 * sizeof(__half));
    size_t sz_bin  = WS_ALIGN((size_t)E * sizeof(unsigned));
    size_t sz_bkt  = WS_ALIGN((size_t)(3 * MAXBUCK + 2) * sizeof(int));
    size_t need_fast = sz_z + sz_bin + sz_bkt;

    char*     ws     = (char*)d_ws;
    __half*   z      = (__half*)ws;
    unsigned* binned = (unsigned*)(ws + sz_z);
    int*      bcnt   = (int*)(ws + sz_z + sz_bin);
    int*      bases  = bcnt + MAXBUCK;            // nbuck+1 entries
    int*      cur    = bases + MAXBUCK + 2;

    int nwgE = (E + 16383) / 16384;

    bool can_fast = (N <= (1 << 17)) && (nbuck <= MAXBUCK) &&
                    (ws_size >= need_fast);

    if (can_fast) {
        hipMemsetAsync(bcnt, 0, (size_t)nbuck * sizeof(int), stream);
        bucket_count<<<nwgE, 256, 0, stream>>>(dst, bcnt, E, nbuck);
        scan_buckets<<<1, 512, 0, stream>>>(bcnt, bases, cur, E, nbuck);
        bin_scatter<<<nwgE, 256, 0, stream>>>(src, dst, cur, binned, E, nbuck);
        gemm_z<<<(N + 255) / 256, 256, 0, stream>>>(h, Wfc, z, N);
        bucket_gather<<<nbuck, 1024, 0, stream>>>(binned, bases, z, out, N);
    } else if (ws_size >= sz_z + WS_ALIGN((size_t)N * sizeof(int))) {
        // atomic scatter-add fallback
        int* deg = (int*)(ws + sz_z);
        hipMemsetAsync(deg, 0, (size_t)N * sizeof(int), stream);
        hipMemsetAsync(out, 0, (size_t)N * 64 * sizeof(float), stream);
        count_deg<<<(E + 255) / 256, 256, 0, stream>>>(dst, deg, E);
        gemm_z<<<(N + 255) / 256, 256, 0, stream>>>(h, Wfc, z, N);
        edge_add<<<(E + 3) / 4, 256, 0, stream>>>(z, src, dst, out, E);
        scale_out<<<(N + 3) / 4, 256, 0, stream>>>(out, deg, N);
    }
}

// Round 7
// 311.881 us; speedup vs baseline: 2.1072x; 1.0580x over previous
//
#include <hip/hip_runtime.h>
#include <hip/hip_fp16.h>

// ---------------------------------------------------------------------------
// GATLayer reduces to:  z = h @ Wfc.T ;  h_out[v] = mean_{e: dst[e]==v} z[src[e]]
// (entmax over singleton dim == 1; entmax over a constant segment == 1/deg)
//
// Fast path: bucket_count (LDS hist, 64-node buckets) -> tiny scan ->
//   bin_scatter (packed (ld<<17|src)) -> gemm (z fp16) -> bucket_gather
//   (256-thr block per bucket: LDS counting sort + register gather).
// 64-node buckets => 1563 blocks, 8 blocks/CU residency, latency-hiding.
// ---------------------------------------------------------------------------

#define WS_ALIGN(x) (((x) + (size_t)255) & ~(size_t)255)
#define BBITS 6
#define BNODES 64             // nodes per bucket
#define CAP 4096              // edges sorted per LDS chunk
#define MAXBUCK 2048

__device__ inline unsigned pack_h2(float a, float b) {
    __half2 h = __floats2half2_rn(a, b);
    return *reinterpret_cast<unsigned*>(&h);
}

// ---- per-bucket edge counts via LDS histogram (few atomics per block) ----
__global__ __launch_bounds__(256) void bucket_count(const int* __restrict__ dst,
                                                    int* __restrict__ bcnt,
                                                    int E, int nbuck) {
    __shared__ int h[MAXBUCK];
    for (int i = threadIdx.x; i < nbuck; i += 256) h[i] = 0;
    __syncthreads();
    int base = blockIdx.x * 16384;
    for (int k = 0; k < 64; k++) {
        int e = base + threadIdx.x + k * 256;
        if (e < E) atomicAdd(&h[dst[e] >> BBITS], 1);
    }
    __syncthreads();
    for (int i = threadIdx.x; i < nbuck; i += 256)
        if (h[i]) atomicAdd(&bcnt[i], h[i]);
}

// ---- exclusive scan of bucket counts (1 block, 1024 thr, nbuck <= 2048) ----
__global__ __launch_bounds__(1024) void scan_buckets(const int* __restrict__ bcnt,
                                                     int* __restrict__ bases,
                                                     int* __restrict__ cur,
                                                     int E, int nbuck) {
    __shared__ int sp[1024];
    int t = threadIdx.x;
    int a = (2 * t < nbuck) ? bcnt[2 * t] : 0;
    int b = (2 * t + 1 < nbuck) ? bcnt[2 * t + 1] : 0;
    sp[t] = a + b;
    __syncthreads();
    for (int off = 1; off < 1024; off <<= 1) {
        int x = (t >= off) ? sp[t - off] : 0;
        __syncthreads();
        sp[t] += x;
        __syncthreads();
    }
    int ex = sp[t] - (a + b);     // exclusive base for element 2t
    if (2 * t < nbuck)     { bases[2 * t] = ex;         cur[2 * t] = ex; }
    if (2 * t + 1 < nbuck) { bases[2 * t + 1] = ex + a; cur[2 * t + 1] = ex + a; }
    if (t == 0) bases[nbuck] = E;
}

// ---- bin edges into bucket-contiguous runs, packed (localdst<<17 | src) ----
__global__ __launch_bounds__(256) void bin_scatter(const int* __restrict__ src,
                                                   const int* __restrict__ dst,
                                                   int* __restrict__ cur,
                                                   unsigned* __restrict__ binned,
                                                   int E, int nbuck) {
    __shared__ int hist[MAXBUCK], gbase[MAXBUCK], cnt2[MAXBUCK];
    int base = blockIdx.x * 16384;
    for (int i = threadIdx.x; i < nbuck; i += 256) { hist[i] = 0; cnt2[i] = 0; }
    __syncthreads();
    for (int k = 0; k < 64; k++) {
        int e = base + threadIdx.x + k * 256;
        if (e < E) atomicAdd(&hist[dst[e] >> BBITS], 1);
    }
    __syncthreads();
    for (int i = threadIdx.x; i < nbuck; i += 256)
        if (hist[i]) gbase[i] = atomicAdd(&cur[i], hist[i]);
    __syncthreads();
    for (int k = 0; k < 64; k++) {
        int e = base + threadIdx.x + k * 256;
        if (e < E) {
            int d = dst[e];
            int b = d >> BBITS;
            int lo = atomicAdd(&cnt2[b], 1);
            binned[gbase[b] + lo] = ((unsigned)(d & (BNODES - 1)) << 17) |
                                    (unsigned)src[e];
        }
    }
}

// ---- z = h @ W.T, fp16 out. W (32 KB) in LDS, broadcast reads. ----
__global__ __launch_bounds__(256) void gemm_z(const float* __restrict__ h,
                                              const float* __restrict__ W,
                                              __half* __restrict__ z, int N) {
    __shared__ float Wl[64 * 128];
    for (int j = threadIdx.x; j < 2048; j += 256) {
        reinterpret_cast<float4*>(Wl)[j] = reinterpret_cast<const float4*>(W)[j];
    }
    __syncthreads();
    int row = blockIdx.x * 256 + threadIdx.x;
    if (row >= N) return;
    float acc[64];
#pragma unroll
    for (int c = 0; c < 64; c++) acc[c] = 0.f;
    const float4* hr = reinterpret_cast<const float4*>(&h[(size_t)row * 128]);
    for (int kv = 0; kv < 32; kv++) {
        float4 hv = hr[kv];
#pragma unroll
        for (int c = 0; c < 64; c++) {
            float4 wv = *reinterpret_cast<const float4*>(&Wl[c * 128 + kv * 4]);
            acc[c] += hv.x * wv.x + hv.y * wv.y + hv.z * wv.z + hv.w * wv.w;
        }
    }
    uint4* zr = reinterpret_cast<uint4*>(&z[(size_t)row * 64]);
#pragma unroll
    for (int c = 0; c < 8; c++) {
        uint4 pk;
        pk.x = pack_h2(acc[8 * c + 0], acc[8 * c + 1]);
        pk.y = pack_h2(acc[8 * c + 2], acc[8 * c + 3]);
        pk.z = pack_h2(acc[8 * c + 4], acc[8 * c + 5]);
        pk.w = pack_h2(acc[8 * c + 6], acc[8 * c + 7]);
        zr[c] = pk;
    }
}

// ---- one 256-thr block per 64-node bucket: LDS counting sort + register
// gather. 4 waves; wave w owns nodes [w*16, w*16+16). lane = output column.
__global__ __launch_bounds__(256) void bucket_gather(
        const unsigned* __restrict__ binned,
        const int* __restrict__ bases,
        const __half* __restrict__ z,
        float* __restrict__ out, int N) {
    __shared__ unsigned sed[CAP];       // srcs sorted by local dst (16 KB)
    __shared__ int hist[BNODES];
    __shared__ int ioff[BNODES];        // inclusive offsets (chunk)
    __shared__ int eoff[BNODES];        // exclusive offsets (chunk)
    __shared__ int curs[BNODES];
    __shared__ int degl[BNODES];        // total degree across chunks

    int b = blockIdx.x;
    int s0 = bases[b], s1 = bases[b + 1];
    int tid = threadIdx.x;
    int wid = tid >> 6, lane = tid & 63;

    if (tid < BNODES) degl[tid] = 0;

    float acc[16];
#pragma unroll
    for (int s = 0; s < 16; s++) acc[s] = 0.f;

    for (int c0 = s0; c0 < s1; c0 += CAP) {
        int cnt = s1 - c0;
        if (cnt > CAP) cnt = CAP;
        if (tid < BNODES) hist[tid] = 0;
        __syncthreads();
        for (int i = tid; i < cnt; i += 256) {
            unsigned p = binned[c0 + i];
            atomicAdd(&hist[(p >> 17) & (BNODES - 1)], 1);
        }
        __syncthreads();
        if (tid < BNODES) ioff[tid] = hist[tid];
        __syncthreads();
        for (int off = 1; off < BNODES; off <<= 1) {
            int x = 0;
            if (tid < BNODES && tid >= off) x = ioff[tid - off];
            __syncthreads();
            if (tid < BNODES) ioff[tid] += x;
            __syncthreads();
        }
        if (tid < BNODES) {
            int ex = ioff[tid] - hist[tid];
            eoff[tid] = ex;
            curs[tid] = ex;
            degl[tid] += hist[tid];
        }
        __syncthreads();
        for (int i = tid; i < cnt; i += 256) {
            unsigned p = binned[c0 + i];
            int ld = (p >> 17) & (BNODES - 1);
            int pos = atomicAdd(&curs[ld], 1);
            sed[pos] = p & 0x1FFFFu;
        }
        __syncthreads();
#pragma unroll
        for (int s = 0; s < 16; s++) {
            int r = wid * 16 + s;
            int e0 = eoff[r], e1 = ioff[r];
            float f0 = 0.f, f1 = 0.f, f2 = 0.f, f3 = 0.f;
            int e = e0;
            for (; e + 4 <= e1; e += 4) {
                int q0 = sed[e], q1 = sed[e + 1], q2 = sed[e + 2], q3 = sed[e + 3];
                f0 += __half2float(z[(size_t)q0 * 64 + lane]);
                f1 += __half2float(z[(size_t)q1 * 64 + lane]);
                f2 += __half2float(z[(size_t)q2 * 64 + lane]);
                f3 += __half2float(z[(size_t)q3 * 64 + lane]);
            }
            for (; e < e1; e++)
                f0 += __half2float(z[(size_t)sed[e] * 64 + lane]);
            acc[s] += (f0 + f1) + (f2 + f3);
        }
        __syncthreads();   // protect sed/ioff/eoff before next chunk
    }
    // write out (coalesced 256B per node row)
    int node0 = b << BBITS;
#pragma unroll
    for (int s = 0; s < 16; s++) {
        int node = node0 + wid * 16 + s;
        if (node < N) {
            int d = degl[wid * 16 + s];
            float sc = (d > 0) ? 1.0f / (float)d : 0.f;
            out[(size_t)node * 64 + lane] = acc[s] * sc;
        }
    }
}

// ---- fallback path (small ws / odd shapes): atomic scatter-add ----
__global__ __launch_bounds__(256) void count_deg(const int* __restrict__ dst,
                                                 int* __restrict__ cnt, int E) {
    int e = blockIdx.x * 256 + threadIdx.x;
    if (e < E) atomicAdd(&cnt[dst[e]], 1);
}

__global__ __launch_bounds__(256) void edge_add(const __half* __restrict__ z,
                                                const int* __restrict__ src,
                                                const int* __restrict__ dst,
                                                float* __restrict__ out, int E) {
    int e = blockIdx.x * 4 + (threadIdx.x >> 6);
    int lane = threadIdx.x & 63;
    if (e >= E) return;
    int s = src[e];
    int d = dst[e];
    float v = __half2float(z[(size_t)s * 64 + lane]);
    atomicAdd(&out[(size_t)d * 64 + lane], v);
}

__global__ __launch_bounds__(256) void scale_out(float* __restrict__ out,
                                                 const int* __restrict__ deg, int N) {
    int v = blockIdx.x * 4 + (threadIdx.x >> 6);
    int lane = threadIdx.x & 63;
    if (v >= N) return;
    int d = deg[v];
    if (d > 0) out[(size_t)v * 64 + lane] *= (1.0f / (float)d);
}

extern "C" void kernel_launch(void* const* d_in, const int* in_sizes, int n_in,
                              void* d_out, int out_size, void* d_ws, size_t ws_size,
                              hipStream_t stream) {
    const float* h   = (const float*)d_in[0];
    const int*   src = (const int*)d_in[2];
    const int*   dst = (const int*)d_in[3];
    const float* Wfc = (const float*)d_in[4];
    float*       out = (float*)d_out;

    int N = in_sizes[0] / 128;
    int E = in_sizes[2];
    (void)n_in; (void)out_size;

    int nbuck = (N + BNODES - 1) >> BBITS;

    size_t sz_z    = WS_ALIGN((size_t)N * 64 * sizeof(__half));
    size_t sz_bin  = WS_ALIGN((size_t)E * sizeof(unsigned));
    size_t sz_bkt  = WS_ALIGN((size_t)(3 * MAXBUCK + 2) * sizeof(int));
    size_t need_fast = sz_z + sz_bin + sz_bkt;

    char*     ws     = (char*)d_ws;
    __half*   z      = (__half*)ws;
    unsigned* binned = (unsigned*)(ws + sz_z);
    int*      bcnt   = (int*)(ws + sz_z + sz_bin);
    int*      bases  = bcnt + MAXBUCK;            // nbuck+1 entries
    int*      cur    = bases + MAXBUCK + 2;

    int nwgE = (E + 16383) / 16384;

    bool can_fast = (N <= (1 << 17)) && (nbuck <= MAXBUCK) &&
                    (ws_size >= need_fast);

    if (can_fast) {
        hipMemsetAsync(bcnt, 0, (size_t)nbuck * sizeof(int), stream);
        bucket_count<<<nwgE, 256, 0, stream>>>(dst, bcnt, E, nbuck);
        scan_buckets<<<1, 1024, 0, stream>>>(bcnt, bases, cur, E, nbuck);
        bin_scatter<<<nwgE, 256, 0, stream>>>(src, dst, cur, binned, E, nbuck);
        gemm_z<<<(N + 255) / 256, 256, 0, stream>>>(h, Wfc, z, N);
        bucket_gather<<<nbuck, 256, 0, stream>>>(binned, bases, z, out, N);
    } else if (ws_size >= sz_z + WS_ALIGN((size_t)N * sizeof(int))) {
        // atomic scatter-add fallback
        int* deg = (int*)(ws + sz_z);
        hipMemsetAsync(deg, 0, (size_t)N * sizeof(int), stream);
        hipMemsetAsync(out, 0, (size_t)N * 64 * sizeof(float), stream);
        count_deg<<<(E + 255) / 256, 256, 0, stream>>>(dst, deg, E);
        gemm_z<<<(N + 255) / 256, 256, 0, stream>>>(h, Wfc, z, N);
        edge_add<<<(E + 3) / 4, 256, 0, stream>>>(z, src, dst, out, E);
        scale_out<<<(N + 3) / 4, 256, 0, stream>>>(out, deg, N);
    }
}